// Round 5
// baseline (827.958 us; speedup 1.0000x reference)
//
#include <hip/hip_runtime.h>
#include <math.h>

typedef unsigned short ushort_t;
using short8  = __attribute__((ext_vector_type(8))) short;
using floatx4 = __attribute__((ext_vector_type(4))) float;

__device__ __forceinline__ ushort_t f2bf(float f) {
  unsigned u = __builtin_bit_cast(unsigned, f);
  u = (u + 0x7fffu + ((u >> 16) & 1u)) >> 16;
  return (ushort_t)u;
}
__device__ __forceinline__ float bf2f(ushort_t u) {
  unsigned v = ((unsigned)u) << 16;
  return __builtin_bit_cast(float, v);
}
__device__ __forceinline__ void load_lds16(const ushort_t* g, ushort_t* l) {
  __builtin_amdgcn_global_load_lds(
      (const __attribute__((address_space(1))) unsigned int*)g,
      (__attribute__((address_space(3))) unsigned int*)l, 16, 0, 0);
}

// ============ fused GEMM + LayerNorm: block = 32 rows x full N=512 ============
// C[M,512] = LN/transform( sum_s A_s[M,Ks] @ W_s^T + bias )
// modes: -1 plain (bf16 [+transposed] write, *scale)
//         0 LN(P)            1 LN(P + R)          2 LN(R + sigmoid(P)*(a+b))
struct Seg { const void* A; const ushort_t* W; int lda, ldw, K, a_f32; };
struct GemmZ {
  ushort_t* Cb; ushort_t* CbT; float* Cf;
  const float* bias;
  const ushort_t* R; const ushort_t* crA; const ushort_t* crB;
  const float* gamma; const float* beta;
  float scale; int gstride;
  int nseg, mmax, mode, gelu;
  Seg seg[6];
};
struct GemmArgs { GemmZ z[9]; };

__global__ __launch_bounds__(512) void gemm_fln(GemmArgs ga) {
  const GemmZ& gz = ga.z[blockIdx.z];
  if ((int)blockIdx.x >= gz.mmax) return;
  __shared__ ushort_t Bs[512 * 32];      // 32 KB: all 512 B-rows (out cols) x 32 k
  __shared__ ushort_t As[32 * 32];       // 2 KB
  __shared__ float redS[32][8], redSS[32][8];
  __shared__ float lnM[32], lnR[32];
  const int tid = threadIdx.x;
  const int wid = tid >> 6, lane = tid & 63, quad = lane >> 4, l16 = lane & 15;
  const int bm = blockIdx.x * 32;
  const int wn = wid * 64;               // this wave's 64-col slice
  floatx4 acc[2][4] = {};

  for (int s = 0; s < gz.nseg; s++) {
    const Seg sg = gz.seg[s];
    for (int k0 = 0; k0 < sg.K; k0 += 32) {
      __syncthreads();
      // B: 512 rows x 32 k = 32 KB via 4 DMA issues/thread
#pragma unroll
      for (int q = 0; q < 4; q++)
        load_lds16(sg.W + (size_t)(q * 128 + (tid >> 2)) * sg.ldw + k0 + (tid & 3) * 8,
                   Bs + q * 4096 + tid * 8);
      // A: 32 rows x 32 k
      if (sg.a_f32) {
        const float* Af = (const float*)sg.A;
        const int ar = tid >> 4, ak = (tid & 15) * 2;
        const float* src = Af + (size_t)(bm + ar) * sg.lda + k0 + ak;
        ushort2 h; h.x = f2bf(src[0]); h.y = f2bf(src[1]);
        *(ushort2*)&As[ar * 32 + ak] = h;
      } else if (tid < 128) {
        load_lds16((const ushort_t*)sg.A + (size_t)(bm + (tid >> 2)) * sg.lda + k0 + (tid & 3) * 8,
                   As + tid * 8);
      }
      __syncthreads();
      short8 af[2], bf[4];
#pragma unroll
      for (int i = 0; i < 2; i++)
        af[i] = *(const short8*)&As[(16 * i + l16) * 32 + quad * 8];
#pragma unroll
      for (int j = 0; j < 4; j++)
        bf[j] = *(const short8*)&Bs[(wn + 16 * j + l16) * 32 + quad * 8];
#pragma unroll
      for (int i = 0; i < 2; i++)
#pragma unroll
        for (int j = 0; j < 4; j++)
          acc[i][j] = __builtin_amdgcn_mfma_f32_16x16x32_bf16(af[i], bf[j], acc[i][j], 0, 0, 0);
    }
  }

  // ---------------- epilogue ----------------
  if (gz.mode < 0) {
#pragma unroll
    for (int i = 0; i < 2; i++)
#pragma unroll
      for (int j = 0; j < 4; j++) {
        const int col = wn + 16 * j + l16;
        const float bb = gz.bias ? gz.bias[col] : 0.f;
#pragma unroll
        for (int r = 0; r < 4; r++) {
          const int rowg = bm + 16 * i + quad * 4 + r;
          const ushort_t bo = f2bf((acc[i][j][r] + bb) * gz.scale);
          if (gz.Cb)  gz.Cb[(size_t)rowg * 512 + col] = bo;
          if (gz.CbT) gz.CbT[(size_t)col * 512 + rowg] = bo;
        }
      }
    return;
  }

  const int task = gz.gstride ? (bm >> 13) : 0;
  const float* gam = gz.gamma + task * gz.gstride;
  const float* bet = gz.beta  + task * gz.gstride;

  float s_p[2][4] = {}, ss_p[2][4] = {};
#pragma unroll
  for (int i = 0; i < 2; i++)
#pragma unroll
    for (int j = 0; j < 4; j++) {
      const int col = wn + 16 * j + l16;
      const float bb = gz.bias ? gz.bias[col] : 0.f;
#pragma unroll
      for (int r = 0; r < 4; r++) {
        const int rowg = bm + 16 * i + quad * 4 + r;
        float x = acc[i][j][r] + bb;
        if (gz.mode == 1) {
          x += bf2f(gz.R[(size_t)rowg * 512 + col]);
        } else if (gz.mode == 2) {
          const float sg = 1.f / (1.f + expf(-x));
          x = bf2f(gz.R[(size_t)rowg * 512 + col]) +
              sg * (bf2f(gz.crA[(size_t)rowg * 512 + col]) +
                    bf2f(gz.crB[(size_t)rowg * 512 + col]));
        }
        acc[i][j][r] = x;
        s_p[i][r] += x; ss_p[i][r] += x * x;
      }
    }
#pragma unroll
  for (int m = 1; m <= 8; m <<= 1)
#pragma unroll
    for (int i = 0; i < 2; i++)
#pragma unroll
      for (int r = 0; r < 4; r++) {
        s_p[i][r]  += __shfl_xor(s_p[i][r],  m, 64);
        ss_p[i][r] += __shfl_xor(ss_p[i][r], m, 64);
      }
  if (l16 == 0) {
#pragma unroll
    for (int i = 0; i < 2; i++)
#pragma unroll
      for (int r = 0; r < 4; r++) {
        redS[16 * i + quad * 4 + r][wid]  = s_p[i][r];
        redSS[16 * i + quad * 4 + r][wid] = ss_p[i][r];
      }
  }
  __syncthreads();
  if (tid < 32) {
    float s = 0.f, ss = 0.f;
#pragma unroll
    for (int wv = 0; wv < 8; wv++) { s += redS[tid][wv]; ss += redSS[tid][wv]; }
    const float mean = s * (1.f / 512.f);
    const float var  = ss * (1.f / 512.f) - mean * mean;
    lnM[tid] = mean; lnR[tid] = rsqrtf(var + 1e-5f);
  }
  __syncthreads();
#pragma unroll
  for (int i = 0; i < 2; i++)
#pragma unroll
    for (int j = 0; j < 4; j++) {
      const int col = wn + 16 * j + l16;
#pragma unroll
      for (int r = 0; r < 4; r++) {
        const int rl = 16 * i + quad * 4 + r;
        const int rowg = bm + rl;
        float y = gam[col] * ((acc[i][j][r] - lnM[rl]) * lnR[rl]) + bet[col];
        if (gz.gelu) y = 0.5f * y * (1.f + erff(y * 0.70710678118f));
        if (gz.Cf) gz.Cf[(size_t)rowg * 512 + col] = y;
        else       gz.Cb[(size_t)rowg * 512 + col] = f2bf(y);
      }
    }
}

// ---------------- merged logit projections: GELU(LN(sigmoid(x)@W + b)) ----------------
__global__ __launch_bounds__(256) void lproj3(
    const float* __restrict__ vl, const float* __restrict__ il, const float* __restrict__ tl,
    const float* __restrict__ Wv, const float* __restrict__ bv,
    const float* __restrict__ Wi, const float* __restrict__ bi,
    const float* __restrict__ Wt, const float* __restrict__ bt,
    const float* __restrict__ lp_g, const float* __restrict__ lp_be,
    ushort_t* __restrict__ out)
{
  const int set = blockIdx.y;
  const float* logits = set == 0 ? vl : set == 1 ? il : tl;
  const int F = set == 0 ? 10 : set == 1 ? 6 : 15;
  const float* W    = set == 0 ? Wv : set == 1 ? Wi : Wt;
  const float* bias = set == 0 ? bv : set == 1 ? bi : bt;
  const float* gamma = lp_g + set * 256;
  const float* beta  = lp_be + set * 256;
  ushort_t* o = out + (size_t)set * 8192 * 256;
  const int wid = threadIdx.x >> 6, lane = threadIdx.x & 63;
  const int row = blockIdx.x * 4 + wid;
  float sg[16];
  for (int f = 0; f < F; f++)
    sg[f] = 1.f / (1.f + expf(-logits[(size_t)row * F + f]));
  float v[4], s = 0.f, ss = 0.f;
#pragma unroll
  for (int j = 0; j < 4; j++) {
    const int c = lane + j * 64;
    float a = bias[c];
    for (int f = 0; f < F; f++) a += sg[f] * W[f * 256 + c];
    v[j] = a; s += a; ss += a * a;
  }
#pragma unroll
  for (int off = 32; off > 0; off >>= 1) {
    s  += __shfl_xor(s,  off, 64);
    ss += __shfl_xor(ss, off, 64);
  }
  const float mean = s * (1.f / 256.f);
  const float var  = ss * (1.f / 256.f) - mean * mean;
  const float rstd = rsqrtf(var + 1e-5f);
#pragma unroll
  for (int j = 0; j < 4; j++) {
    const int c = lane + j * 64;
    float y = gamma[c] * ((v[j] - mean) * rstd) + beta[c];
    y = 0.5f * y * (1.f + erff(y * 0.70710678118f));
    o[(size_t)row * 256 + c] = f2bf(y);
  }
}

// ---------------- prep: weight conversions + cb, one launch ----------------
struct PrepArgs {
  const float *mha_in_W, *mha_out_W, *mha_in_b, *mha_out_b;
  const float *hp_W, *gate_W, *fus_W1, *fus_W2;
  ushort_t *Wvbf, *hpWt, *gateWt, *fusW1t, *fusW2t, *WoT;
  float *cb;
};

__global__ __launch_bounds__(256) void prep(PrepArgs pa) {
  __shared__ float tsh[32][33];
  const int b = blockIdx.x, tid = threadIdx.x;
  if (b < 4096) {                        // Wv slice -> bf16
    const int z = b >> 10, blk = b & 1023;
    const int idx = blk * 256 + tid, r = idx >> 9, c = idx & 511;
    pa.Wvbf[(size_t)z * 262144 + idx] =
        f2bf(pa.mha_in_W[(size_t)z * 786432 + (size_t)r * 1536 + 1024 + c]);
    return;
  }
  if (b >= 9600) {                       // cb_z = bv_z @ Wo_z + bo_z
    const int u2 = b - 9600, z = u2 >> 1, part = u2 & 1;
    const int n = part * 256 + tid;
    const float* bv = pa.mha_in_b + z * 1536 + 1024;
    const float* Wo = pa.mha_out_W + (size_t)z * 262144;
    float a = pa.mha_out_b[z * 512 + n];
    for (int k = 0; k < 512; k++) a += bv[k] * Wo[(size_t)k * 512 + n];
    pa.cb[z * 512 + n] = a;
    return;
  }
  const float* tin; ushort_t* tout; int K, N, u; size_t izs, ozs;
  if (b < 5632)      { u = b - 4096; tin = pa.hp_W;      tout = pa.hpWt;   K = 1024; N = 512; izs = 524288; ozs = 524288; }
  else if (b < 7168) { u = b - 5632; tin = pa.gate_W;    tout = pa.gateWt; K = 1024; N = 512; izs = 524288; ozs = 524288; }
  else if (b < 8320) { u = b - 7168; tin = pa.fus_W1;    tout = pa.fusW1t; K = 2304; N = 512; izs = 0;      ozs = 0; }
  else if (b < 8576) { u = b - 8320; tin = pa.fus_W2;    tout = pa.fusW2t; K = 512;  N = 512; izs = 0;      ozs = 0; }
  else               { u = b - 8576; tin = pa.mha_out_W; tout = pa.WoT;    K = 512;  N = 512; izs = 262144; ozs = 262144; }
  const int nbx = N / 32, perz = nbx * (K / 32);
  const int z = u / perz, rem = u % perz, bx = rem % nbx, by = rem / nbx;
  tin += (size_t)z * izs; tout += (size_t)z * ozs;
  const int n0 = bx * 32, k0 = by * 32;
  const int tx = tid & 31, ty = tid >> 5;
#pragma unroll
  for (int r = 0; r < 32; r += 8)
    tsh[ty + r][tx] = tin[(size_t)(k0 + ty + r) * N + n0 + tx];
  __syncthreads();
#pragma unroll
  for (int r = 0; r < 32; r += 8)
    tout[(size_t)(n0 + ty + r) * K + k0 + tx] = f2bf(tsh[tx][ty + r]);
}

// bias2[t][n] = gate_b[t][n] + 0.5*sum_k (cb[m1]+cb[m2])[k] * gate_W[t][512+k][n]
__global__ __launch_bounds__(256) void bias2_k(
    const float* __restrict__ cb, const float* __restrict__ gate_W,
    const float* __restrict__ gate_b, float* __restrict__ out)
{
  const int t = blockIdx.z;
  const int m1[3] = {1, 1, 2}, m2[3] = {2, 3, 3};
  const float* c1 = cb + m1[t] * 512;
  const float* c2 = cb + m2[t] * 512;
  const float* W = gate_W + (size_t)t * 524288 + (size_t)512 * 512;
  const int n = blockIdx.x * 256 + threadIdx.x;
  float a = gate_b[t * 512 + n];
  for (int k = 0; k < 512; k++) a += 0.5f * (c1[k] + c2[k]) * W[(size_t)k * 512 + n];
  out[t * 512 + n] = a;
}

extern "C" void kernel_launch(void* const* d_in, const int* in_sizes, int n_in,
                              void* d_out, int out_size, void* d_ws, size_t ws_size,
                              hipStream_t stream)
{
  const float* verb_hidden   = (const float*)d_in[0];
  const float* verb_logits   = (const float*)d_in[1];
  const float* inst_hidden   = (const float*)d_in[2];
  const float* inst_logits   = (const float*)d_in[3];
  const float* target_hidden = (const float*)d_in[4];
  const float* target_logits = (const float*)d_in[5];
  const float* hp_W  = (const float*)d_in[6];
  const float* hp_b  = (const float*)d_in[7];
  const float* hp_g  = (const float*)d_in[8];
  const float* hp_be = (const float*)d_in[9];
  const float* lp_W_verb   = (const float*)d_in[10];
  const float* lp_b_verb   = (const float*)d_in[11];
  const float* lp_W_inst   = (const float*)d_in[12];
  const float* lp_b_inst   = (const float*)d_in[13];
  const float* lp_W_target = (const float*)d_in[14];
  const float* lp_b_target = (const float*)d_in[15];
  const float* lp_g  = (const float*)d_in[16];
  const float* lp_be = (const float*)d_in[17];
  const float* mha_in_W  = (const float*)d_in[18];
  const float* mha_in_b  = (const float*)d_in[19];
  const float* mha_out_W = (const float*)d_in[20];
  const float* mha_out_b = (const float*)d_in[21];
  const float* n1_g  = (const float*)d_in[22];
  const float* n1_be = (const float*)d_in[23];
  const float* n2_g  = (const float*)d_in[24];
  const float* n2_be = (const float*)d_in[25];
  const float* gate_W = (const float*)d_in[26];
  const float* gate_b = (const float*)d_in[27];
  const float* fus_W1 = (const float*)d_in[28];
  const float* fus_b1 = (const float*)d_in[29];
  const float* fus_g1 = (const float*)d_in[30];
  const float* fus_ge1= (const float*)d_in[31];
  const float* fus_W2 = (const float*)d_in[32];
  const float* fus_b2 = (const float*)d_in[33];
  const float* fus_g2 = (const float*)d_in[34];
  const float* fus_ge2= (const float*)d_in[35];

  char* w = (char*)d_ws;
  const size_t S2 = (size_t)8192 * 512;
  const size_t MB = 1024 * 1024;
  ushort_t* crossbf = (ushort_t*)(w);              // 48 MB; later gbf
  ushort_t* gbf     = (ushort_t*)(w);
  ushort_t* hbf     = (ushort_t*)(w + 48 * MB);    // 24 MB; later fbf
  ushort_t* fbf     = (ushort_t*)(w + 48 * MB);
  ushort_t* ebf     = (ushort_t*)(w + 72 * MB);    // 24 MB
  ushort_t* lbf     = (ushort_t*)(w + 96 * MB);    // 12 MB
  char* wp = w + 108 * MB;
  ushort_t* hpWt    = (ushort_t*)(wp);
  ushort_t* gateWt  = (ushort_t*)(wp + 3145728);
  ushort_t* fusW1t  = (ushort_t*)(wp + 6291456);
  ushort_t* fusW2t  = (ushort_t*)(wp + 8650752);
  ushort_t* WoT     = (ushort_t*)(wp + 9175040);
  ushort_t* Wvbf    = (ushort_t*)(wp + 11272192);
  ushort_t* CWt     = (ushort_t*)(wp + 13369344);
  ushort_t* CWplain = (ushort_t*)(wp + 15466496);
  ushort_t* Gt      = (ushort_t*)(wp + 17563648);
  float*    cb      = (float*)(wp + 20709376);
  float*    bias2   = (float*)(wp + 20717568);

  dim3 blk256(256), blk512(512);
  const int mods[3][2] = {{1, 2}, {1, 3}, {2, 3}};
  const int srcs[3][2] = {{1, 2}, {0, 2}, {0, 1}};

  // L1: prep (weights only)
  {
    PrepArgs pa;
    pa.mha_in_W = mha_in_W; pa.mha_out_W = mha_out_W;
    pa.mha_in_b = mha_in_b; pa.mha_out_b = mha_out_b;
    pa.hp_W = hp_W; pa.gate_W = gate_W; pa.fus_W1 = fus_W1; pa.fus_W2 = fus_W2;
    pa.Wvbf = Wvbf; pa.hpWt = hpWt; pa.gateWt = gateWt;
    pa.fusW1t = fusW1t; pa.fusW2t = fusW2t; pa.WoT = WoT; pa.cb = cb;
    prep<<<9608, blk256, 0, stream>>>(pa);
  }

  // L2: fold1 — CW_z = Wv_z @ Wo_z (plain + transposed bf16)
  {
    GemmArgs ga{};
    for (int z = 0; z < 4; z++) {
      GemmZ& g = ga.z[z];
      g.Cb = CWplain + (size_t)z * 262144; g.CbT = CWt + (size_t)z * 262144;
      g.scale = 1.f; g.nseg = 1; g.mmax = 16; g.mode = -1;
      g.seg[0] = {Wvbf + (size_t)z * 262144, WoT + (size_t)z * 262144, 512, 512, 512, 0};
    }
    gemm_fln<<<dim3(16, 1, 4), blk512, 0, stream>>>(ga);
  }

  // L3: folded gate biases
  bias2_k<<<dim3(2, 1, 3), blk256, 0, stream>>>(cb, gate_W, gate_b, bias2);

  // L4: stage A (z=0..2, f32 A direct, fused LN+GELU -> hbf) + fold2 (z=3..8)
  {
    GemmArgs ga{};
    const float* xs[3] = {verb_hidden, inst_hidden, target_hidden};
    for (int z = 0; z < 3; z++) {
      GemmZ& g = ga.z[z];
      g.Cb = hbf + (size_t)z * S2; g.bias = hp_b + z * 512;
      g.gamma = hp_g + z * 512; g.beta = hp_be + z * 512;
      g.scale = 1.f; g.nseg = 1; g.mmax = 256; g.mode = 0; g.gelu = 1;
      g.seg[0] = {xs[z], hpWt + (size_t)z * 524288, 1024, 1024, 1024, 1};
    }
    for (int idx = 0; idx < 6; idx++) {
      const int t = idx >> 1, u = idx & 1, m = mods[t][u];
      GemmZ& g = ga.z[3 + idx];
      g.Cb = Gt + (size_t)idx * 262144; g.scale = 0.5f; g.nseg = 1; g.mmax = 16; g.mode = -1;
      g.seg[0] = {gateWt + (size_t)t * 524288 + 512, CWplain + (size_t)m * 262144, 1024, 512, 512, 0};
    }
    gemm_fln<<<dim3(256, 1, 9), blk512, 0, stream>>>(ga);
  }

  // L5: logit projections
  lproj3<<<dim3(2048, 3), blk256, 0, stream>>>(verb_logits, inst_logits, target_logits,
      lp_W_verb, lp_b_verb, lp_W_inst, lp_b_inst, lp_W_target, lp_b_target,
      lp_g, lp_be, lbf);

  // L6: stage C — e = LN(h + h@CW0 + cb0), M=24576, fused residual LN
  {
    GemmArgs ga{};
    GemmZ& g = ga.z[0];
    g.Cb = ebf; g.bias = cb; g.R = hbf;
    g.gamma = n1_g; g.beta = n1_be; g.gstride = 512;
    g.scale = 1.f; g.nseg = 1; g.mmax = 768; g.mode = 1;
    g.seg[0] = {hbf, CWt, 512, 512, 512, 0};
    gemm_fln<<<dim3(768, 1, 1), blk512, 0, stream>>>(ga);
  }

  // L7: cross — a' = 0.5*(e_src @ CW_mod + cb_mod), plain bf16
  {
    GemmArgs ga{};
    for (int t = 0; t < 3; t++)
      for (int u = 0; u < 2; u++) {
        GemmZ& g = ga.z[2 * t + u];
        g.Cb = crossbf + (size_t)(2 * t + u) * S2;
        g.bias = cb + mods[t][u] * 512; g.scale = 0.5f;
        g.nseg = 1; g.mmax = 256; g.mode = -1;
        g.seg[0] = {ebf + (size_t)srcs[t][u] * S2, CWt + (size_t)mods[t][u] * 262144, 512, 512, 512, 0};
      }
    gemm_fln<<<dim3(256, 1, 6), blk512, 0, stream>>>(ga);
  }

  // L8: gate+fuse — f = LN(e + sigmoid(gateP)*(a'+b')), fused epilogue
  {
    GemmArgs ga{};
    for (int t = 0; t < 3; t++) {
      GemmZ& g = ga.z[t];
      g.Cb = fbf + (size_t)t * S2; g.bias = bias2 + t * 512;
      g.R = ebf + (size_t)t * S2;
      g.crA = crossbf + (size_t)(2 * t) * S2;
      g.crB = crossbf + (size_t)(2 * t + 1) * S2;
      g.gamma = n2_g + t * 512; g.beta = n2_be + t * 512;
      g.scale = 1.f; g.nseg = 3; g.mmax = 256; g.mode = 2;
      g.seg[0] = {ebf + (size_t)t * S2,           gateWt + (size_t)t * 524288,       512, 1024, 512, 0};
      g.seg[1] = {ebf + (size_t)srcs[t][0] * S2,  Gt + (size_t)(2 * t) * 262144,     512, 512,  512, 0};
      g.seg[2] = {ebf + (size_t)srcs[t][1] * S2,  Gt + (size_t)(2 * t + 1) * 262144, 512, 512,  512, 0};
    }
    gemm_fln<<<dim3(256, 1, 3), blk512, 0, stream>>>(ga);
  }

  // L9: fus1 — g = GELU(LN([f0,f1,f2,l0,l1,l2]@W1 + b1))
  {
    GemmArgs ga{};
    GemmZ& g = ga.z[0];
    g.Cb = gbf; g.bias = fus_b1;
    g.gamma = fus_g1; g.beta = fus_ge1;
    g.scale = 1.f; g.nseg = 6; g.mmax = 256; g.mode = 0; g.gelu = 1;
    g.seg[0] = {fbf,                          fusW1t,        512, 2304, 512, 0};
    g.seg[1] = {fbf + S2,                     fusW1t + 512,  512, 2304, 512, 0};
    g.seg[2] = {fbf + 2 * S2,                 fusW1t + 1024, 512, 2304, 512, 0};
    g.seg[3] = {lbf,                          fusW1t + 1536, 256, 2304, 256, 0};
    g.seg[4] = {lbf + (size_t)8192 * 256,     fusW1t + 1792, 256, 2304, 256, 0};
    g.seg[5] = {lbf + (size_t)2 * 8192 * 256, fusW1t + 2048, 256, 2304, 256, 0};
    gemm_fln<<<dim3(256, 1, 1), blk512, 0, stream>>>(ga);
  }

  // L10: fus2 — out = LN(g@W2 + b2), f32 to d_out
  {
    GemmArgs ga{};
    GemmZ& g = ga.z[0];
    g.Cf = (float*)d_out; g.bias = fus_b2;
    g.gamma = fus_g2; g.beta = fus_ge2;
    g.scale = 1.f; g.nseg = 1; g.mmax = 256; g.mode = 0;
    g.seg[0] = {gbf, fusW2t, 512, 512, 512, 0};
    gemm_fln<<<dim3(256, 1, 1), blk512, 0, stream>>>(ga);
  }
}

// Round 6
// 686.362 us; speedup vs baseline: 1.2063x; 1.2063x over previous
//
#include <hip/hip_runtime.h>
#include <math.h>

typedef unsigned short ushort_t;
using short8  = __attribute__((ext_vector_type(8))) short;
using floatx4 = __attribute__((ext_vector_type(4))) float;

__device__ __forceinline__ ushort_t f2bf(float f) {
  unsigned u = __builtin_bit_cast(unsigned, f);
  u = (u + 0x7fffu + ((u >> 16) & 1u)) >> 16;
  return (ushort_t)u;
}
__device__ __forceinline__ float bf2f(ushort_t u) {
  unsigned v = ((unsigned)u) << 16;
  return __builtin_bit_cast(float, v);
}
__device__ __forceinline__ void load_lds16(const ushort_t* g, ushort_t* l) {
  __builtin_amdgcn_global_load_lds(
      (const __attribute__((address_space(1))) unsigned int*)g,
      (__attribute__((address_space(3))) unsigned int*)l, 16, 0, 0);
}

// ---------------- segmented batched GEMM (bf16 in, bf16 out) ----------------
// C[M,512] = (sum_s A_s[M,Ks] @ W_s^T + bias) * scale ; W_s stored [512,Ks] bf16
struct Seg { const ushort_t* A; const ushort_t* W; int lda, ldw, K; };
struct GemmZ {
  ushort_t* Cb;        // row-major bf16 (may be null)
  ushort_t* CbT;       // transposed bf16 (folds only, M=512)
  const float* bias;
  float scale; int nseg; int mmax;
  Seg seg[6];
};
struct GemmArgs { GemmZ z[12]; };

template <int BM>
__global__ __launch_bounds__(256) void gemm_bt(GemmArgs ga) {
  const GemmZ& gz = ga.z[blockIdx.z];
  if ((int)blockIdx.x >= gz.mmax) return;
  __shared__ ushort_t As[BM * 32];
  __shared__ ushort_t Bs[128 * 32];
  const int tid = threadIdx.x;
  const int wid = tid >> 6, lane = tid & 63, quad = lane >> 4, l16 = lane & 15;
  const int bm = blockIdx.x * BM, bn = blockIdx.y * 128;
  constexpr int MI = BM / 32;
  const int wm = (wid & 1) * (BM / 2), wn = (wid >> 1) * 64;
  floatx4 acc[MI][4] = {};
  const int srow = tid >> 2, scol = (tid & 3) * 8;
  ushort_t* aL = As + tid * 8;
  ushort_t* bL = Bs + tid * 8;

  for (int s = 0; s < gz.nseg; s++) {
    const Seg sg = gz.seg[s];
    const ushort_t* aG = sg.A + (size_t)(bm + srow) * sg.lda + scol;
    const ushort_t* bG = sg.W + (size_t)(bn + srow) * sg.ldw + scol;
    const size_t astep = (size_t)64 * sg.lda;
    const size_t bstep = (size_t)64 * sg.ldw;
    for (int k0 = 0; k0 < sg.K; k0 += 32) {
      __syncthreads();
      load_lds16(aG + k0, aL);
      if (BM == 128) load_lds16(aG + k0 + astep, aL + 2048);
      load_lds16(bG + k0, bL);
      load_lds16(bG + k0 + bstep, bL + 2048);
      __syncthreads();
      short8 af[MI], bf[4];
#pragma unroll
      for (int i = 0; i < MI; i++)
        af[i] = *(const short8*)&As[(wm + 16 * i + l16) * 32 + quad * 8];
#pragma unroll
      for (int j = 0; j < 4; j++)
        bf[j] = *(const short8*)&Bs[(wn + 16 * j + l16) * 32 + quad * 8];
#pragma unroll
      for (int i = 0; i < MI; i++)
#pragma unroll
        for (int j = 0; j < 4; j++)
          acc[i][j] = __builtin_amdgcn_mfma_f32_16x16x32_bf16(af[i], bf[j], acc[i][j], 0, 0, 0);
    }
  }

#pragma unroll
  for (int i = 0; i < MI; i++) {
#pragma unroll
    for (int j = 0; j < 4; j++) {
      const int colg = bn + wn + 16 * j + l16;
      const float bb = gz.bias ? gz.bias[colg] : 0.f;
#pragma unroll
      for (int r = 0; r < 4; r++) {
        const int rowg = bm + wm + 16 * i + quad * 4 + r;
        const float v = (acc[i][j][r] + bb) * gz.scale;
        const ushort_t bo = f2bf(v);
        if (gz.Cb)  gz.Cb[(size_t)rowg * 512 + colg] = bo;
        if (gz.CbT) gz.CbT[(size_t)colg * 512 + rowg] = bo;
      }
    }
  }
}

// ---------------- LayerNorm family (N=512), one wave/row, bf16 preacts ----------------
// mode 0: x = P ; mode 1: x = P + R ; mode 2: x = R + sigmoid(P)*(a'+b')
__global__ __launch_bounds__(256) void row_ln(
    const ushort_t* __restrict__ P, const ushort_t* __restrict__ R,
    const ushort_t* __restrict__ cross,
    const float* __restrict__ gamma, const float* __restrict__ beta, int gstride,
    ushort_t* __restrict__ outb, float* __restrict__ outf, int mode, int gelu)
{
  const size_t S2 = (size_t)8192 * 512;
  const int wid = threadIdx.x >> 6, lane = threadIdx.x & 63;
  const int row = blockIdx.x * 4 + wid;
  const int t = row >> 13;
  const float* g  = gamma + t * gstride;
  const float* be = beta + t * gstride;
  const ushort_t* p = P + (size_t)row * 512;
  const ushort_t* ar = nullptr;
  if (mode == 2) ar = cross + (size_t)(2 * t) * S2 + (size_t)(row & 8191) * 512;
  float v[8], s = 0.f, ss = 0.f;
#pragma unroll
  for (int j = 0; j < 8; j++) {
    const int c = lane + j * 64;
    float x = bf2f(p[c]);
    if (mode == 2) {
      const float sg = 1.f / (1.f + expf(-x));
      x = bf2f(R[(size_t)row * 512 + c]) + sg * (bf2f(ar[c]) + bf2f(ar[S2 + c]));
    } else if (mode == 1) {
      x += bf2f(R[(size_t)row * 512 + c]);
    }
    v[j] = x; s += x; ss += x * x;
  }
#pragma unroll
  for (int off = 32; off > 0; off >>= 1) {
    s  += __shfl_xor(s,  off, 64);
    ss += __shfl_xor(ss, off, 64);
  }
  const float mean = s * (1.f / 512.f);
  const float var  = ss * (1.f / 512.f) - mean * mean;
  const float rstd = rsqrtf(var + 1e-5f);
#pragma unroll
  for (int j = 0; j < 8; j++) {
    const int c = lane + j * 64;
    float y = g[c] * ((v[j] - mean) * rstd) + be[c];
    if (gelu) y = 0.5f * y * (1.f + erff(y * 0.70710678118f));
    if (outb) outb[(size_t)row * 512 + c] = f2bf(y);
    else      outf[(size_t)row * 512 + c] = y;
  }
}

// ---------------- merged logit projections ----------------
__global__ __launch_bounds__(256) void lproj3(
    const float* __restrict__ vl, const float* __restrict__ il, const float* __restrict__ tl,
    const float* __restrict__ Wv, const float* __restrict__ bv,
    const float* __restrict__ Wi, const float* __restrict__ bi,
    const float* __restrict__ Wt, const float* __restrict__ bt,
    const float* __restrict__ lp_g, const float* __restrict__ lp_be,
    ushort_t* __restrict__ out)
{
  const int set = blockIdx.y;
  const float* logits = set == 0 ? vl : set == 1 ? il : tl;
  const int F = set == 0 ? 10 : set == 1 ? 6 : 15;
  const float* W    = set == 0 ? Wv : set == 1 ? Wi : Wt;
  const float* bias = set == 0 ? bv : set == 1 ? bi : bt;
  const float* gamma = lp_g + set * 256;
  const float* beta  = lp_be + set * 256;
  ushort_t* o = out + (size_t)set * 8192 * 256;
  const int wid = threadIdx.x >> 6, lane = threadIdx.x & 63;
  const int row = blockIdx.x * 4 + wid;
  float sg[16];
  for (int f = 0; f < F; f++)
    sg[f] = 1.f / (1.f + expf(-logits[(size_t)row * F + f]));
  float v[4], s = 0.f, ss = 0.f;
#pragma unroll
  for (int j = 0; j < 4; j++) {
    const int c = lane + j * 64;
    float a = bias[c];
    for (int f = 0; f < F; f++) a += sg[f] * W[f * 256 + c];
    v[j] = a; s += a; ss += a * a;
  }
#pragma unroll
  for (int off = 32; off > 0; off >>= 1) {
    s  += __shfl_xor(s,  off, 64);
    ss += __shfl_xor(ss, off, 64);
  }
  const float mean = s * (1.f / 256.f);
  const float var  = ss * (1.f / 256.f) - mean * mean;
  const float rstd = rsqrtf(var + 1e-5f);
#pragma unroll
  for (int j = 0; j < 4; j++) {
    const int c = lane + j * 64;
    float y = gamma[c] * ((v[j] - mean) * rstd) + beta[c];
    y = 0.5f * y * (1.f + erff(y * 0.70710678118f));
    o[(size_t)row * 256 + c] = f2bf(y);
  }
}

// ---------------- prep: all conversions + cb, one launch ----------------
struct PrepArgs {
  const float *vh, *ih, *th;
  const float *mha_in_W, *mha_out_W, *mha_in_b, *mha_out_b;
  const float *hp_W, *gate_W, *fus_W1, *fus_W2;
  ushort_t *xbf, *Wvbf, *hpWt, *gateWt, *fusW1t, *fusW2t, *WoT;
  float *cb;
};

__global__ __launch_bounds__(256) void prep(PrepArgs pa) {
  __shared__ float tsh[32][33];
  const int b = blockIdx.x, tid = threadIdx.x;
  if (b < 24576) {                       // hidden f32 -> bf16
    const int mat = b >> 13, blk = b & 8191;
    const float* src = mat == 0 ? pa.vh : mat == 1 ? pa.ih : pa.th;
    const size_t i = (size_t)blk * 256 + tid;
    const float4 f = ((const float4*)src)[i];
    ushort4 o; o.x = f2bf(f.x); o.y = f2bf(f.y); o.z = f2bf(f.z); o.w = f2bf(f.w);
    ((ushort4*)(pa.xbf + (size_t)mat * 8192 * 1024))[i] = o;
    return;
  }
  if (b < 28672) {                       // Wv slice -> bf16
    const int u = b - 24576, z = u >> 10, blk = u & 1023;
    const int idx = blk * 256 + tid, r = idx >> 9, c = idx & 511;
    pa.Wvbf[(size_t)z * 262144 + idx] =
        f2bf(pa.mha_in_W[(size_t)z * 786432 + (size_t)r * 1536 + 1024 + c]);
    return;
  }
  if (b >= 34176) {                      // cb_z = bv_z @ Wo_z + bo_z
    const int u2 = b - 34176, z = u2 >> 1, part = u2 & 1;
    const int n = part * 256 + tid;
    const float* bv = pa.mha_in_b + z * 1536 + 1024;
    const float* Wo = pa.mha_out_W + (size_t)z * 262144;
    float a = pa.mha_out_b[z * 512 + n];
    for (int k = 0; k < 512; k++) a += bv[k] * Wo[(size_t)k * 512 + n];
    pa.cb[z * 512 + n] = a;
    return;
  }
  const float* tin; ushort_t* tout; int K, N, u; size_t izs, ozs;
  if (b < 30208)      { u = b - 28672; tin = pa.hp_W;      tout = pa.hpWt;   K = 1024; N = 512; izs = 524288; ozs = 524288; }
  else if (b < 31744) { u = b - 30208; tin = pa.gate_W;    tout = pa.gateWt; K = 1024; N = 512; izs = 524288; ozs = 524288; }
  else if (b < 32896) { u = b - 31744; tin = pa.fus_W1;    tout = pa.fusW1t; K = 2304; N = 512; izs = 0;      ozs = 0; }
  else if (b < 33152) { u = b - 32896; tin = pa.fus_W2;    tout = pa.fusW2t; K = 512;  N = 512; izs = 0;      ozs = 0; }
  else                { u = b - 33152; tin = pa.mha_out_W; tout = pa.WoT;    K = 512;  N = 512; izs = 262144; ozs = 262144; }
  const int nbx = N / 32, perz = nbx * (K / 32);
  const int z = u / perz, rem = u % perz, bx = rem % nbx, by = rem / nbx;
  tin += (size_t)z * izs; tout += (size_t)z * ozs;
  const int n0 = bx * 32, k0 = by * 32;
  const int tx = tid & 31, ty = tid >> 5;
#pragma unroll
  for (int r = 0; r < 32; r += 8)
    tsh[ty + r][tx] = tin[(size_t)(k0 + ty + r) * N + n0 + tx];
  __syncthreads();
#pragma unroll
  for (int r = 0; r < 32; r += 8)
    tout[(size_t)(n0 + ty + r) * K + k0 + tx] = f2bf(tsh[tx][ty + r]);
}

// bias2[t][n] = gate_b[t][n] + 0.5*sum_k (cb[m1]+cb[m2])[k] * gate_W[t][512+k][n]
__global__ __launch_bounds__(256) void bias2_k(
    const float* __restrict__ cb, const float* __restrict__ gate_W,
    const float* __restrict__ gate_b, float* __restrict__ out)
{
  const int t = blockIdx.z;
  const int m1[3] = {1, 1, 2}, m2[3] = {2, 3, 3};
  const float* c1 = cb + m1[t] * 512;
  const float* c2 = cb + m2[t] * 512;
  const float* W = gate_W + (size_t)t * 524288 + (size_t)512 * 512;
  const int n = blockIdx.x * 256 + threadIdx.x;
  float a = gate_b[t * 512 + n];
  for (int k = 0; k < 512; k++) a += 0.5f * (c1[k] + c2[k]) * W[(size_t)k * 512 + n];
  out[t * 512 + n] = a;
}

extern "C" void kernel_launch(void* const* d_in, const int* in_sizes, int n_in,
                              void* d_out, int out_size, void* d_ws, size_t ws_size,
                              hipStream_t stream)
{
  const float* verb_hidden   = (const float*)d_in[0];
  const float* verb_logits   = (const float*)d_in[1];
  const float* inst_hidden   = (const float*)d_in[2];
  const float* inst_logits   = (const float*)d_in[3];
  const float* target_hidden = (const float*)d_in[4];
  const float* target_logits = (const float*)d_in[5];
  const float* hp_W  = (const float*)d_in[6];
  const float* hp_b  = (const float*)d_in[7];
  const float* hp_g  = (const float*)d_in[8];
  const float* hp_be = (const float*)d_in[9];
  const float* lp_W_verb   = (const float*)d_in[10];
  const float* lp_b_verb   = (const float*)d_in[11];
  const float* lp_W_inst   = (const float*)d_in[12];
  const float* lp_b_inst   = (const float*)d_in[13];
  const float* lp_W_target = (const float*)d_in[14];
  const float* lp_b_target = (const float*)d_in[15];
  const float* lp_g  = (const float*)d_in[16];
  const float* lp_be = (const float*)d_in[17];
  const float* mha_in_W  = (const float*)d_in[18];
  const float* mha_in_b  = (const float*)d_in[19];
  const float* mha_out_W = (const float*)d_in[20];
  const float* mha_out_b = (const float*)d_in[21];
  const float* n1_g  = (const float*)d_in[22];
  const float* n1_be = (const float*)d_in[23];
  const float* n2_g  = (const float*)d_in[24];
  const float* n2_be = (const float*)d_in[25];
  const float* gate_W = (const float*)d_in[26];
  const float* gate_b = (const float*)d_in[27];
  const float* fus_W1 = (const float*)d_in[28];
  const float* fus_b1 = (const float*)d_in[29];
  const float* fus_g1 = (const float*)d_in[30];
  const float* fus_ge1= (const float*)d_in[31];
  const float* fus_W2 = (const float*)d_in[32];
  const float* fus_b2 = (const float*)d_in[33];
  const float* fus_g2 = (const float*)d_in[34];
  const float* fus_ge2= (const float*)d_in[35];

  char* w = (char*)d_ws;
  const size_t S2 = (size_t)8192 * 512;
  const size_t MB = 1024 * 1024;
  // region0 48MB: xbf (L1-L4) -> crossbf (L9-L10) -> gbf (L12-L13)
  ushort_t* xbf     = (ushort_t*)(w);
  ushort_t* crossbf = (ushort_t*)(w);
  ushort_t* gbf     = (ushort_t*)(w);
  ushort_t* Pbig    = (ushort_t*)(w + 48 * MB);   // 24 MB bf16 preacts
  ushort_t* hbf     = (ushort_t*)(w + 72 * MB);   // 24 MB; later fbf
  ushort_t* fbf     = (ushort_t*)(w + 72 * MB);
  ushort_t* ebf     = (ushort_t*)(w + 96 * MB);   // 24 MB
  ushort_t* lbf     = (ushort_t*)(w + 120 * MB);  // 12 MB
  char* wp = w + 132 * MB;
  ushort_t* hpWt    = (ushort_t*)(wp);
  ushort_t* gateWt  = (ushort_t*)(wp + 3145728);
  ushort_t* fusW1t  = (ushort_t*)(wp + 6291456);
  ushort_t* fusW2t  = (ushort_t*)(wp + 8650752);
  ushort_t* WoT     = (ushort_t*)(wp + 9175040);
  ushort_t* Wvbf    = (ushort_t*)(wp + 11272192);
  ushort_t* CWt     = (ushort_t*)(wp + 13369344);
  ushort_t* CWplain = (ushort_t*)(wp + 15466496);
  ushort_t* Gt      = (ushort_t*)(wp + 17563648);
  float*    cb      = (float*)(wp + 20709376);
  float*    bias2   = (float*)(wp + 20717568);
  ushort_t* P2      = (ushort_t*)(w + 156 * MB);  // 24 MB second preact

  dim3 blk(256);
  const int mods[3][2] = {{1, 2}, {1, 3}, {2, 3}};
  const int srcs[3][2] = {{1, 2}, {0, 2}, {0, 1}};

  // L1: prep
  {
    PrepArgs pa;
    pa.vh = verb_hidden; pa.ih = inst_hidden; pa.th = target_hidden;
    pa.mha_in_W = mha_in_W; pa.mha_out_W = mha_out_W;
    pa.mha_in_b = mha_in_b; pa.mha_out_b = mha_out_b;
    pa.hp_W = hp_W; pa.gate_W = gate_W; pa.fus_W1 = fus_W1; pa.fus_W2 = fus_W2;
    pa.xbf = xbf; pa.Wvbf = Wvbf; pa.hpWt = hpWt; pa.gateWt = gateWt;
    pa.fusW1t = fusW1t; pa.fusW2t = fusW2t; pa.WoT = WoT; pa.cb = cb;
    prep<<<34184, blk, 0, stream>>>(pa);
  }

  // L2: fold1 — CW_z = Wv_z @ Wo_z (plain + transposed)
  {
    GemmArgs ga{};
    for (int z = 0; z < 4; z++) {
      GemmZ& g = ga.z[z];
      g.Cb = CWplain + (size_t)z * 262144; g.CbT = CWt + (size_t)z * 262144;
      g.scale = 1.f; g.nseg = 1; g.mmax = 4;
      g.seg[0] = {Wvbf + (size_t)z * 262144, WoT + (size_t)z * 262144, 512, 512, 512};
    }
    gemm_bt<128><<<dim3(4, 4, 4), blk, 0, stream>>>(ga);
  }

  // L3: folded gate biases
  bias2_k<<<dim3(2, 1, 3), blk, 0, stream>>>(cb, gate_W, gate_b, bias2);

  // L4: stage A split-K (z=0..5) + fold2 G (z=6..11)
  {
    GemmArgs ga{};
    for (int t = 0; t < 3; t++)
      for (int h = 0; h < 2; h++) {
        GemmZ& g = ga.z[2 * t + h];
        g.Cb = (h == 0 ? Pbig : P2) + (size_t)t * S2;
        g.bias = (h == 0) ? hp_b + t * 512 : nullptr;
        g.scale = 1.f; g.nseg = 1; g.mmax = 64;
        g.seg[0] = {xbf + (size_t)t * 8192 * 1024 + h * 512,
                    hpWt + (size_t)t * 524288 + h * 512, 1024, 1024, 512};
      }
    for (int idx = 0; idx < 6; idx++) {
      const int t = idx >> 1, u = idx & 1, m = mods[t][u];
      GemmZ& g = ga.z[6 + idx];
      g.Cb = Gt + (size_t)idx * 262144; g.scale = 0.5f; g.nseg = 1; g.mmax = 4;
      g.seg[0] = {gateWt + (size_t)t * 524288 + 512, CWplain + (size_t)m * 262144, 1024, 512, 512};
    }
    gemm_bt<128><<<dim3(64, 4, 12), blk, 0, stream>>>(ga);
  }

  // L5: logit projections
  lproj3<<<dim3(2048, 3), blk, 0, stream>>>(verb_logits, inst_logits, target_logits,
      lp_W_verb, lp_b_verb, lp_W_inst, lp_b_inst, lp_W_target, lp_b_target,
      lp_g, lp_be, lbf);

  // L6: h = GELU(LN(P0 + P1))
  row_ln<<<6144, blk, 0, stream>>>(Pbig, P2, nullptr, hp_g, hp_be, 512,
                                   hbf, nullptr, 1, 1);

  // L7: stage C preact = h @ CW0 + cb0 (M=24576, BM=64 for occupancy)
  {
    GemmArgs ga{};
    GemmZ& g = ga.z[0];
    g.Cb = Pbig; g.bias = cb; g.scale = 1.f; g.nseg = 1; g.mmax = 384;
    g.seg[0] = {hbf, CWt, 512, 512, 512};
    gemm_bt<64><<<dim3(384, 4, 1), blk, 0, stream>>>(ga);
  }
  // L8: e = LN(h + P)
  row_ln<<<6144, blk, 0, stream>>>(Pbig, hbf, nullptr, n1_g, n1_be, 512,
                                   ebf, nullptr, 1, 0);

  // L9: cross (z=0..5) + gate (z=6..8) in one launch
  {
    GemmArgs ga{};
    for (int t = 0; t < 3; t++)
      for (int u = 0; u < 2; u++) {
        GemmZ& g = ga.z[2 * t + u];
        g.Cb = crossbf + (size_t)(2 * t + u) * S2;
        g.bias = cb + mods[t][u] * 512; g.scale = 0.5f; g.nseg = 1; g.mmax = 64;
        g.seg[0] = {ebf + (size_t)srcs[t][u] * S2, CWt + (size_t)mods[t][u] * 262144, 512, 512, 512};
      }
    for (int t = 0; t < 3; t++) {
      GemmZ& g = ga.z[6 + t];
      g.Cb = Pbig + (size_t)t * S2; g.bias = bias2 + t * 512;
      g.scale = 1.f; g.nseg = 3; g.mmax = 64;
      g.seg[0] = {ebf + (size_t)t * S2,           gateWt + (size_t)t * 524288, 512, 1024, 512};
      g.seg[1] = {ebf + (size_t)srcs[t][0] * S2,  Gt + (size_t)(2 * t) * 262144,     512, 512, 512};
      g.seg[2] = {ebf + (size_t)srcs[t][1] * S2,  Gt + (size_t)(2 * t + 1) * 262144, 512, 512, 512};
    }
    gemm_bt<128><<<dim3(64, 4, 9), blk, 0, stream>>>(ga);
  }

  // L10: f = LN(e + sigmoid(P)*(a'+b'))
  row_ln<<<6144, blk, 0, stream>>>(Pbig, ebf, crossbf, n2_g, n2_be, 512,
                                   fbf, nullptr, 2, 0);

  // L11: fus1 split into two z (f-segs / l-segs)
  {
    GemmArgs ga{};
    GemmZ& g0 = ga.z[0];
    g0.Cb = Pbig; g0.bias = fus_b1; g0.scale = 1.f; g0.nseg = 3; g0.mmax = 128;
    g0.seg[0] = {fbf,          fusW1t,        512, 2304, 512};
    g0.seg[1] = {fbf + S2,     fusW1t + 512,  512, 2304, 512};
    g0.seg[2] = {fbf + 2 * S2, fusW1t + 1024, 512, 2304, 512};
    GemmZ& g1 = ga.z[1];
    g1.Cb = P2; g1.scale = 1.f; g1.nseg = 3; g1.mmax = 128;
    g1.seg[0] = {lbf,                          fusW1t + 1536, 256, 2304, 256};
    g1.seg[1] = {lbf + (size_t)8192 * 256,     fusW1t + 1792, 256, 2304, 256};
    g1.seg[2] = {lbf + (size_t)2 * 8192 * 256, fusW1t + 2048, 256, 2304, 256};
    gemm_bt<64><<<dim3(128, 4, 2), blk, 0, stream>>>(ga);
  }
  // L12: g = GELU(LN(P0 + P1))
  row_ln<<<2048, blk, 0, stream>>>(Pbig, P2, nullptr, fus_g1, fus_ge1, 0,
                                   gbf, nullptr, 1, 1);
  // L13: fus2 preact
  {
    GemmArgs ga{};
    GemmZ& g = ga.z[0];
    g.Cb = Pbig; g.bias = fus_b2; g.scale = 1.f; g.nseg = 1; g.mmax = 128;
    g.seg[0] = {gbf, fusW2t, 512, 512, 512};
    gemm_bt<64><<<dim3(128, 4, 1), blk, 0, stream>>>(ga);
  }
  // L14: out = LN(P), f32
  row_ln<<<2048, blk, 0, stream>>>(Pbig, nullptr, nullptr, fus_g2, fus_ge2, 0,
                                   nullptr, (float*)d_out, 0, 0);
}